// Round 1
// baseline (1344.565 us; speedup 1.0000x reference)
//
#include <hip/hip_runtime.h>
#include <hip/hip_bf16.h>

// TGCN graph convolution: out = (L @ [inputs|hidden]) @ W + b
// N=16384, B=2, F=32, G=16, OUT=16.  Dominant cost: stream L (1.07 GB fp32).
// Strategy: batch-fused bf16 MFMA GEMM C[16384,96] = L @ Xt^T, split-K=4,
// global_load_lds(16B) staging with XOR swizzle baked into src addresses.
// Workspace: Xt bf16 3 MB @ ws+0, Cp fp32 partials 25.2 MB @ ws+4MB (~29.2 MB).

#define NN   16384
#define FF   32
#define GG   16
#define OUTD 16
#define C96  96
#define BM   64
#define BK   64
#define SPLITK 4
#define KCHUNK (NN / SPLITK)
#define KITERS (KCHUNK / BK)

typedef __attribute__((ext_vector_type(8))) short short8;
typedef __attribute__((ext_vector_type(4))) float f32x4;

using as1_void = __attribute__((address_space(1))) void;
using as3_void = __attribute__((address_space(3))) void;

__device__ __forceinline__ unsigned short f2bf(float f) {
  __hip_bfloat16 h = __float2bfloat16(f);
  return __builtin_bit_cast(unsigned short, h);
}

// ---------------------------------------------------------------------------
// Prep: Xt[c][n] bf16, c = b*48 + (f | 32+g), via LDS transpose (coalesced).
// ---------------------------------------------------------------------------
__global__ __launch_bounds__(256) void prep_xt(const float* __restrict__ inp,
                                               const float* __restrict__ hid,
                                               unsigned short* __restrict__ xt) {
  __shared__ float lds_cat[C96][64];
  const int tid = threadIdx.x;
  const int n0 = blockIdx.x * 64;

  // inputs: per batch 64 nodes x 32 f = 512 float4
#pragma unroll
  for (int r = 0; r < 2; ++r) {
    int fi = tid + r * 256;       // 0..511
    int n = fi >> 3;
    int f4 = fi & 7;
#pragma unroll
    for (int b = 0; b < 2; ++b) {
      const float4* src = (const float4*)(inp + ((size_t)b * NN + (n0 + n)) * FF) + f4;
      float4 v = *src;
      int c = b * 48 + f4 * 4;
      lds_cat[c + 0][n] = v.x;
      lds_cat[c + 1][n] = v.y;
      lds_cat[c + 2][n] = v.z;
      lds_cat[c + 3][n] = v.w;
    }
  }
  // hidden: per batch 64 nodes x 16 g = 256 float4
  {
    int n = tid >> 2;
    int g4 = tid & 3;
#pragma unroll
    for (int b = 0; b < 2; ++b) {
      const float4* src = (const float4*)(hid + ((size_t)b * NN + (n0 + n)) * GG) + g4;
      float4 v = *src;
      int c = b * 48 + 32 + g4 * 4;
      lds_cat[c + 0][n] = v.x;
      lds_cat[c + 1][n] = v.y;
      lds_cat[c + 2][n] = v.z;
      lds_cat[c + 3][n] = v.w;
    }
  }
  __syncthreads();
  // write Xt rows: 768 16B-units, 3 per thread, coalesced along n
#pragma unroll
  for (int r = 0; r < 3; ++r) {
    int u = tid + r * 256;
    int c = u >> 3;
    int nn = (u & 7) * 8;
    short8 o;
#pragma unroll
    for (int j = 0; j < 8; ++j) o[j] = (short)f2bf(lds_cat[c][nn + j]);
    *(short8*)(xt + (size_t)c * NN + n0 + nn) = o;
  }
}

// ---------------------------------------------------------------------------
// Main: Cp[split][m][c96] = partial L @ X over this block's K range.
// A tile 64x64 fp32 (16 KB), B tile 96x64 bf16 (12 KB), single-buffered.
// XOR swizzle: A unit (row,cu4) at slot row*16 + (cu4 ^ (row&15));
//              B unit (c,kg8)  at slot c*8   + (kg8 ^ (c&7)).
// Swizzle is applied in the per-lane GLOBAL src address of global_load_lds,
// so LDS fills contiguously (wave-uniform base + lane*16) but lands swizzled.
// ---------------------------------------------------------------------------
__global__ __launch_bounds__(256, 4) void spmm_main(const float* __restrict__ L,
                                                    const unsigned short* __restrict__ xt,
                                                    float* __restrict__ cp) {
  __shared__ __align__(16) float lds_a[BM * BK];            // 16 KB
  __shared__ __align__(16) unsigned short lds_b[C96 * BK];  // 12 KB

  const int tid = threadIdx.x;
  const int wave = tid >> 6;
  const int lane = tid & 63;
  const int m0 = blockIdx.x * BM;
  const int kbase = blockIdx.y * KCHUNK;

  // staging source/dest (k0-invariant parts)
  const float* asrc[4];
  float* adst[4];
#pragma unroll
  for (int a = 0; a < 4; ++a) {
    int s = wave * 256 + a * 64 + lane;
    int row = s >> 4;
    int cu = (s & 15) ^ (row & 15);
    asrc[a] = L + (size_t)(m0 + row) * NN + kbase + cu * 4;
    adst[a] = lds_a + (wave * 256 + a * 64) * 4;  // wave-uniform
  }
  const unsigned short* bsrc[3];
  unsigned short* bdst[3];
#pragma unroll
  for (int bi = 0; bi < 3; ++bi) {
    int s = wave * 192 + bi * 64 + lane;
    int c = s >> 3;
    int kg = (s & 7) ^ (c & 7);
    bsrc[bi] = xt + (size_t)c * NN + kbase + kg * 8;
    bdst[bi] = lds_b + (wave * 192 + bi * 64) * 8;  // wave-uniform
  }

  // fragment LDS offsets (iteration-invariant)
  const int rowA = wave * 16 + (lane & 15);
  const int lq = lane >> 4;
  int aoff[2][2];
#pragma unroll
  for (int kk = 0; kk < 2; ++kk) {
    int cu0 = kk * 8 + lq * 2;
    aoff[kk][0] = (rowA * 16 + (cu0 ^ (rowA & 15))) * 4;
    aoff[kk][1] = (rowA * 16 + ((cu0 + 1) ^ (rowA & 15))) * 4;
  }
  int boff[2][6];
#pragma unroll
  for (int kk = 0; kk < 2; ++kk)
#pragma unroll
    for (int t = 0; t < 6; ++t) {
      int c = t * 16 + (lane & 15);
      int kg = kk * 4 + lq;
      boff[kk][t] = (c * 8 + (kg ^ (c & 7))) * 8;
    }

  f32x4 acc[6];
#pragma unroll
  for (int t = 0; t < 6; ++t) acc[t] = (f32x4){0.f, 0.f, 0.f, 0.f};

  for (int it = 0; it < KITERS; ++it) {
    const int ko = it * BK;
#pragma unroll
    for (int a = 0; a < 4; ++a)
      __builtin_amdgcn_global_load_lds((const as1_void*)(asrc[a] + ko),
                                       (as3_void*)adst[a], 16, 0, 0);
#pragma unroll
    for (int bi = 0; bi < 3; ++bi)
      __builtin_amdgcn_global_load_lds((const as1_void*)(bsrc[bi] + ko),
                                       (as3_void*)bdst[bi], 16, 0, 0);
    __syncthreads();

#pragma unroll
    for (int kk = 0; kk < 2; ++kk) {
      f32x4 a0 = *(const f32x4*)(lds_a + aoff[kk][0]);
      f32x4 a1 = *(const f32x4*)(lds_a + aoff[kk][1]);
      short8 af;
      af[0] = (short)f2bf(a0[0]);
      af[1] = (short)f2bf(a0[1]);
      af[2] = (short)f2bf(a0[2]);
      af[3] = (short)f2bf(a0[3]);
      af[4] = (short)f2bf(a1[0]);
      af[5] = (short)f2bf(a1[1]);
      af[6] = (short)f2bf(a1[2]);
      af[7] = (short)f2bf(a1[3]);
#pragma unroll
      for (int t = 0; t < 6; ++t) {
        short8 bf = *(const short8*)(lds_b + boff[kk][t]);
        acc[t] = __builtin_amdgcn_mfma_f32_16x16x32_bf16(af, bf, acc[t], 0, 0, 0);
      }
    }
    __syncthreads();
  }

  // store split-K partial tile (each region written exactly once)
  float* cpd = cp + ((size_t)blockIdx.y * NN + m0) * C96;
#pragma unroll
  for (int t = 0; t < 6; ++t) {
    int col = t * 16 + (lane & 15);
#pragma unroll
    for (int r = 0; r < 4; ++r) {
      int row = wave * 16 + lq * 4 + r;
      cpd[(size_t)row * C96 + col] = acc[t][r];
    }
  }
}

// ---------------------------------------------------------------------------
// Epilogue: sum split-K partials, apply W[48x16] + bias, write out[2][N][16].
// ---------------------------------------------------------------------------
__global__ __launch_bounds__(256) void epilogue(const float* __restrict__ cp,
                                                const float* __restrict__ w,
                                                const float* __restrict__ bias,
                                                float* __restrict__ out) {
  __shared__ float lds_c[64 * 97];   // 64 nodes x 96 cols, +1 pad per row
  __shared__ float lds_w[48 * 16];
  __shared__ float lds_bias[16];
  const int tid = threadIdx.x;
  const int n0 = blockIdx.x * 64;

  for (int i = tid; i < 768; i += 256) lds_w[i] = w[i];
  if (tid < 16) lds_bias[tid] = bias[tid];

  const size_t base = (size_t)n0 * C96;
#pragma unroll
  for (int i = 0; i < 24; ++i) {
    int e = tid + i * 256;   // 0..6143 over [64 x 96]
    float s = 0.f;
#pragma unroll
    for (int sp = 0; sp < 4; ++sp)
      s += cp[(size_t)sp * (NN * C96) + base + e];
    lds_c[e + e / 96] = s;   // node*97 + col
  }
  __syncthreads();

  const int node = tid >> 2;
  const int b = (tid >> 1) & 1;
  const int o0 = (tid & 1) * 8;
  const float* crow = &lds_c[node * 97 + b * 48];
  float accv[8];
#pragma unroll
  for (int o = 0; o < 8; ++o) accv[o] = lds_bias[o0 + o];
#pragma unroll
  for (int j = 0; j < 48; ++j) {
    float cv = crow[j];
#pragma unroll
    for (int o = 0; o < 8; ++o) accv[o] += cv * lds_w[j * 16 + o0 + o];
  }
  size_t ob = (size_t)b * (NN * OUTD) + (size_t)(n0 + node) * OUTD + o0;
  float4 v0 = {accv[0], accv[1], accv[2], accv[3]};
  float4 v1 = {accv[4], accv[5], accv[6], accv[7]};
  *(float4*)(out + ob) = v0;
  *(float4*)(out + ob + 4) = v1;
}

extern "C" void kernel_launch(void* const* d_in, const int* in_sizes, int n_in,
                              void* d_out, int out_size, void* d_ws, size_t ws_size,
                              hipStream_t stream) {
  (void)in_sizes; (void)n_in; (void)out_size; (void)ws_size;
  const float* inp = (const float*)d_in[0];   // [2,16384,32]
  const float* hid = (const float*)d_in[1];   // [2,16384*16]
  const float* lap = (const float*)d_in[2];   // [16384,16384]
  const float* wts = (const float*)d_in[3];   // [48,16]
  const float* bia = (const float*)d_in[4];   // [16]
  float* out = (float*)d_out;                 // [2,16384*16]

  unsigned short* xt = (unsigned short*)d_ws;                  // 3 MB bf16
  float* cp = (float*)((char*)d_ws + (4u << 20));              // 25.2 MB fp32

  prep_xt<<<NN / 64, 256, 0, stream>>>(inp, hid, xt);
  spmm_main<<<dim3(NN / BM, SPLITK), 256, 0, stream>>>(lap, xt, cp);
  epilogue<<<NN / 64, 256, 0, stream>>>(cp, wts, bia, out);
}